// Round 10
// baseline (98.155 us; speedup 1.0000x reference)
//
#include <hip/hip_runtime.h>

#define BATCH 4
#define NN    2048
#define TOPK  30
#define VDIM  124
#define EDIM  35

typedef unsigned long long ull;
typedef unsigned int uint;
typedef float f32x2 __attribute__((ext_vector_type(2)));
#define SENT   (~0ull)
#define SENTHI 0xFFFFFFFFu
#define INV2PI 0.15915494309189535f

__device__ __forceinline__ float rnorm3_eps(float s) {
    return 1.0f / sqrtf(fmaxf(s, 1e-8f));
}

__device__ __forceinline__ float wsum64(float v) {
#pragma unroll
    for (int m = 32; m; m >>= 1) v += __shfl_xor(v, m);
    return v;
}

// full-wave u32 min; result valid in lane 63.
__device__ __forceinline__ uint wmin_u32(uint v) {
    uint t;
    t = (uint)__builtin_amdgcn_update_dpp((int)v, (int)v, 0x111, 0xf, 0xf, false); v = v < t ? v : t; // row_shr:1
    t = (uint)__builtin_amdgcn_update_dpp((int)v, (int)v, 0x112, 0xf, 0xf, false); v = v < t ? v : t; // row_shr:2
    t = (uint)__builtin_amdgcn_update_dpp((int)v, (int)v, 0x114, 0xf, 0xf, false); v = v < t ? v : t; // row_shr:4
    t = (uint)__builtin_amdgcn_update_dpp((int)v, (int)v, 0x118, 0xf, 0xf, false); v = v < t ? v : t; // row_shr:8
    t = (uint)__builtin_amdgcn_update_dpp((int)v, (int)v, 0x142, 0xf, 0xf, false); v = v < t ? v : t; // row_bcast:15
    t = (uint)__builtin_amdgcn_update_dpp((int)v, (int)v, 0x143, 0xf, 0xf, false); v = v < t ? v : t; // row_bcast:31
    return v;
}

// raw squared-distance bits — pinned f32 order; within-lane selection only.
__device__ __forceinline__ uint d2_bits(const float* __restrict__ sx,
                                        const float2* __restrict__ syz, int j,
                                        float cx, float cy, float cz) {
    const float  x  = sx[j];
    const float2 yz = syz[j];
    const float dx = x - cx, dy = yz.x - cy, dz = yz.y - cz;
    const float d2 = __fadd_rn(__fadd_rn(__fmul_rn(dx, dx), __fmul_rn(dy, dy)),
                               __fmul_rn(dz, dz));
    return __float_as_uint(d2);
}

// exact D bits (bit-identical to reference): sqrt(d2 + 1e-6)
__device__ __forceinline__ uint d2_to_D(uint d2b) {
    return __float_as_uint(sqrtf(__fadd_rn(__uint_as_float(d2b), 1e-6f)));
}

__device__ __forceinline__ void ld_atom(const float* __restrict__ Xb, int f,
                                        float& x, float& y, float& z) {
    const int q = f / 3, r = f - q * 3;
    const float* p = Xb + q * 15 + r * 3;
    x = p[0]; y = p[1]; z = p[2];
}

// ===== fused kernel: 8 rows per 256-thread block, 2 rows per wave =====
// grid = 1024 = exactly 4 blocks/CU x 256 CUs with 25-KB LDS (residency 6/CU)
// -> ALL blocks co-resident, zero dispatch-tail quantization (R9's 39% occ
// was one full round + a 512-block 1/3-filled second round).
__global__ __launch_bounds__(256) void fused_kernel(
    const float* __restrict__ X,
    const float* __restrict__ Wh_n, const float* __restrict__ Ws_n,
    const float* __restrict__ bs_n, const float* __restrict__ Wv_n,
    const float* __restrict__ Wh_e, const float* __restrict__ Ws_e,
    const float* __restrict__ bs_e, const float* __restrict__ Wv_e,
    const float* __restrict__ gamma_n, const float* __restrict__ beta_n,
    const float* __restrict__ gamma_e, const float* __restrict__ beta_e,
    float* __restrict__ outV, float* __restrict__ outE, float* __restrict__ outIdx)
{
    __shared__ float  sCAx[NN];      // 8 KB
    __shared__ float2 sCAyz[NN];     // 16 KB
    __shared__ float  sEP[96];       // bs_e | gamma_e | beta_e

    const int tid  = threadIdx.x;
    const int wid  = tid >> 6;
    const int lane = tid & 63;
    const int rbase = blockIdx.x * 8;                // 8 | 2048 -> same batch per block
    const int b    = rbase >> 11;
    const float* Xb = X + (size_t)b * NN * 15;

    for (int idx = tid; idx < NN; idx += 256) {
        const float* p = Xb + idx * 15 + 3;
        sCAx[idx]  = p[0];
        sCAyz[idx] = make_float2(p[1], p[2]);
    }
    if (tid < 32) {
        sEP[tid]      = bs_e[tid];
        sEP[32 + tid] = gamma_e[tid];
        sEP[64 + tid] = beta_e[tid];
    }
    __syncthreads();

    for (int rr = 0; rr < 2; ++rr) {
        const int row = rbase + (rr << 2) + wid;
        const int i   = row & (NN - 1);

        const float cix = sCAx[i];
        const float2 ciyz = sCAyz[i];
        const float ciy = ciyz.x, ciz = ciyz.y;

        // ---- Phase A: per-lane sorted top-4 by raw d2 bits (column j = lane + 64s)
        uint l0hi = SENTHI, l0lo = 0, l1hi = SENTHI, l1lo = 0;
        uint l2hi = SENTHI, l2lo = 0, l3hi = SENTHI, l3lo = 0;
#pragma unroll 8
        for (int s = 0; s < NN / 64; ++s) {
            uint khi = d2_bits(sCAx, sCAyz, (s << 6) + lane, cix, ciy, ciz);
            uint klo = (uint)((s << 6) + lane);
            {
                const bool c = khi < l0hi;
                const uint nh = c ? khi : l0hi, nl = c ? klo : l0lo;
                const uint xh = c ? l0hi : khi, xl = c ? l0lo : klo;
                l0hi = nh; l0lo = nl; khi = xh; klo = xl;
            }
            {
                const bool c = khi < l1hi;
                const uint nh = c ? khi : l1hi, nl = c ? klo : l1lo;
                const uint xh = c ? l1hi : khi, xl = c ? l1lo : klo;
                l1hi = nh; l1lo = nl; khi = xh; klo = xl;
            }
            {
                const bool c = khi < l2hi;
                const uint nh = c ? khi : l2hi, nl = c ? klo : l2lo;
                const uint xh = c ? l2hi : khi, xl = c ? l2lo : klo;
                l2hi = nh; l2lo = nl; khi = xh; klo = xl;
            }
            {
                const bool c = khi < l3hi;
                l3hi = c ? khi : l3hi; l3lo = c ? klo : l3lo;
            }
        }
        // convert survivors to exact D bits
        l0hi = d2_to_D(l0hi); l1hi = d2_to_D(l1hi);
        l2hi = d2_to_D(l2hi); l3hi = d2_to_D(l3hi);

        // ---- Phase B: 30 extractions in D-space; lanes 2e,2e+1 latch edge e
        uint myhi = SENTHI, mylo = 0u;
        for (int it = 0; it < TOPK; ++it) {
            const uint mhi = (uint)__builtin_amdgcn_readlane((int)wmin_u32(l0hi), 63);
            const ull bal = __ballot(l0hi == mhi);
            uint mlo;
            if (__popcll(bal) == 1) {
                mlo = (uint)__builtin_amdgcn_readlane((int)l0lo, __ffsll((long long)bal) - 1);
            } else {
                const uint lom = (l0hi == mhi) ? l0lo : 0xFFFFFFFFu;
                mlo = (uint)__builtin_amdgcn_readlane((int)wmin_u32(lom), 63);
            }
            if ((lane >> 1) == it) { myhi = mhi; mylo = mlo; }

            const bool own = (l0hi == mhi) && (l0lo == mlo);
            if (own) {
                l0hi = l1hi; l0lo = l1lo;
                l1hi = l2hi; l1lo = l2lo;
                l2hi = l3hi; l2lo = l3lo;
                l3hi = SENTHI; l3lo = 0;
            }

            const bool need = own && (l0hi == SENTHI);
            if (__any((int)need)) {                 // rare deep-refill (exact D keys)
                const ull m = (((ull)mhi) << 32) | mlo;
                ull best = SENT;
#pragma unroll 4
                for (int s = 0; s < NN / 64; ++s) {
                    const int j = (s << 6) + lane;
                    const ull k = (((ull)d2_to_D(d2_bits(sCAx, sCAyz, j, cix, ciy, ciz))) << 32) | (uint)j;
                    if (k > m && k < best) best = k;
                }
                if (need) { l0hi = (uint)(best >> 32); l0lo = (uint)best; }
            }
        }

        // ---- Phase C: lanes 2e (h=0) / 2e+1 (h=1) split edge e's 32 LN outputs
        if (lane < 2 * TOPK) {
            const int e = lane >> 1, h = lane & 1;
            const uint j = mylo;
            const float D = __uint_as_float(myhi);

            const float xj = sCAx[j];
            const float2 yzj = sCAyz[j];
            const float ux = xj - cix, uy = yzj.x - ciy, uz = yzj.y - ciz;
            const float inv = rnorm3_eps(ux * ux + uy * uy + uz * uz);

            const float whe = Wh_e[0], wve = Wv_e[0];
            const float hx = ux * inv * whe, hy = uy * inv * whe, hz = uz * inv * whe;
            const float vno = sqrtf(fmaxf(hx * hx + hy * hy + hz * hz, 1e-8f));

            float sx[33];
#pragma unroll
            for (int r = 0; r < 16; ++r) {
                const float t = (D - (float)(20.0 * r / 15.0)) * 0.8f;
                sx[r] = __expf(-t * t);
            }
            const float FRT[8] = {1.0f, 0.31622776601683794f, 0.1f,
                                  0.031622776601683794f, 0.01f,
                                  0.0031622776601683794f, 0.001f,
                                  0.00031622776601683794f};
            const float offset = (float)(int)j - (float)i;
#pragma unroll
            for (int p = 0; p < 8; ++p) {
                const float ang = offset * FRT[p];
                const float rev = __builtin_amdgcn_fractf(ang * INV2PI);
                sx[16 + p] = __builtin_amdgcn_cosf(rev);
                sx[24 + p] = __builtin_amdgcn_sinf(rev);
            }
            sx[32] = vno;

            const int ob = h * 16;
            f32x2 acc2[8];
            const f32x2* bs2 = (const f32x2*)&sEP[ob];
#pragma unroll
            for (int q = 0; q < 8; ++q) acc2[q] = bs2[q];
#pragma unroll
            for (int k = 0; k < 33; ++k) {
                const f32x2* w2 = (const f32x2*)&Ws_e[k * 32 + ob];  // L1-resident (4.2 KB)
                const float v = sx[k];
                const f32x2 vv = {v, v};
#pragma unroll
                for (int q = 0; q < 8; ++q)
                    acc2[q] = __builtin_elementwise_fma(vv, w2[q], acc2[q]);
            }

            float su = 0.f;
#pragma unroll
            for (int q = 0; q < 8; ++q) { su += acc2[q][0]; su += acc2[q][1]; }
            su += __shfl_xor(su, 1);
            const float mu = su * (1.0f / 32.0f);
            float vs = 0.f;
#pragma unroll
            for (int q = 0; q < 8; ++q) {
                const float d0 = acc2[q][0] - mu, d1 = acc2[q][1] - mu;
                vs += d0 * d0; vs += d1 * d1;
            }
            vs += __shfl_xor(vs, 1);
            const float rstd = 1.0f / sqrtf(vs * (1.0f / 32.0f) + 1e-3f);

            const size_t ebase = ((size_t)row * TOPK + e) * EDIM;
            if (h == 0) {
                outE[ebase + 0] = hx * wve;
                outE[ebase + 1] = hy * wve;
                outE[ebase + 2] = hz * wve;
                outIdx[(size_t)row * TOPK + e] = (float)j;
            }
#pragma unroll
            for (int o = 0; o < 16; ++o)
                outE[ebase + 3 + ob + o] =
                    (acc2[o >> 1][o & 1] - mu) * rstd * sEP[32 + ob + o] + sEP[64 + ob + o];
        }

        // ================= NODE features for node = row (same wave) =================
        {
            const int n = i;
            const float* Xr = Xb + n * 15;

            float nx = Xr[0] - Xr[3], ny = Xr[1] - Xr[4], nz = Xr[2] - Xr[5];
            float cx = Xr[6] - Xr[3], cy = Xr[7] - Xr[4], cz = Xr[8] - Xr[5];
            {
                const float ic = rnorm3_eps(cx * cx + cy * cy + cz * cz);
                cx *= ic; cy *= ic; cz *= ic;
                const float in_ = rnorm3_eps(nx * nx + ny * ny + nz * nz);
                nx *= in_; ny *= in_; nz *= in_;
            }
            float bx = cx + nx, by = cy + ny, bz = cz + nz;
            {
                const float ib = rnorm3_eps(bx * bx + by * by + bz * bz);
                bx *= ib; by *= ib; bz *= ib;
            }
            float px = cy * nz - cz * ny, py = cz * nx - cx * nz, pz = cx * ny - cy * nx;
            {
                const float ip = rnorm3_eps(px * px + py * py + pz * pz);
                px *= ip; py *= ip; pz *= ip;
            }
            const float S13 = 0.5773502691896258f, S23 = 0.816496580927726f;
            const float vx = -bx * S13 - px * S23;
            const float vy = -by * S13 - py * S23;
            const float vz = -bz * S13 - pz * S23;

            // fwd/bwd from staged CA (bit-identical values)
            float fx = 0.f, fy = 0.f, fz = 0.f, wx = 0.f, wy = 0.f, wz = 0.f;
            if (n < NN - 1) {
                const float xn = sCAx[n + 1];
                const float2 yzn = sCAyz[n + 1];
                float tx = xn - cix, ty = yzn.x - ciy, tz = yzn.y - ciz;
                const float it = rnorm3_eps(tx * tx + ty * ty + tz * tz);
                fx = tx * it; fy = ty * it; fz = tz * it;
            }
            if (n > 0) {
                const float xp = sCAx[n - 1];
                const float2 yzp = sCAyz[n - 1];
                float tx = cix - xp, ty = ciy - yzp.x, tz = ciz - yzp.y;
                const float it = rnorm3_eps(tx * tx + ty * ty + tz * tz);
                wx = -tx * it; wy = -ty * it; wz = -tz * it;
            }

            float ang[3];
#pragma unroll
            for (int t = 0; t < 3; ++t) {
                const int m = 3 * n + t - 1;
                if (m < 0 || m > 3 * NN - 4) { ang[t] = 0.f; continue; }
                float a0x, a0y, a0z, a1x, a1y, a1z, a2x, a2y, a2z, a3x, a3y, a3z;
                ld_atom(Xb, m,     a0x, a0y, a0z);
                ld_atom(Xb, m + 1, a1x, a1y, a1z);
                ld_atom(Xb, m + 2, a2x, a2y, a2z);
                ld_atom(Xb, m + 3, a3x, a3y, a3z);
                float u2x = a1x - a0x, u2y = a1y - a0y, u2z = a1z - a0z;
                float u1x = a2x - a1x, u1y = a2y - a1y, u1z = a2z - a1z;
                float u0x = a3x - a2x, u0y = a3y - a2y, u0z = a3z - a2z;
                { const float s = rnorm3_eps(u2x*u2x + u2y*u2y + u2z*u2z); u2x*=s; u2y*=s; u2z*=s; }
                { const float s = rnorm3_eps(u1x*u1x + u1y*u1y + u1z*u1z); u1x*=s; u1y*=s; u1z*=s; }
                { const float s = rnorm3_eps(u0x*u0x + u0y*u0y + u0z*u0z); u0x*=s; u0y*=s; u0z*=s; }
                float n2x = u2y*u1z - u2z*u1y, n2y = u2z*u1x - u2x*u1z, n2z = u2x*u1y - u2y*u1x;
                float n1x = u1y*u0z - u1z*u0y, n1y = u1z*u0x - u1x*u0z, n1z = u1x*u0y - u1y*u0x;
                { const float s = rnorm3_eps(n2x*n2x + n2y*n2y + n2z*n2z); n2x*=s; n2y*=s; n2z*=s; }
                { const float s = rnorm3_eps(n1x*n1x + n1y*n1y + n1z*n1z); n1x*=s; n1y*=s; n1z*=s; }
                float cd = n2x*n1x + n2y*n1y + n2z*n1z;
                cd = fminf(fmaxf(cd, -1.0f + 1e-7f), 1.0f - 1e-7f);
                const float sg0 = u2x*n1x + u2y*n1y + u2z*n1z;
                const float sg = (sg0 > 0.f) ? 1.f : ((sg0 < 0.f) ? -1.f : 0.f);
                ang[t] = sg * acosf(cd);
            }

            float vh0[8], vh1[8], vh2[8], nrm[8];
#pragma unroll
            for (int hh = 0; hh < 8; ++hh) {
                const float w0 = Wh_n[hh], w1 = Wh_n[8 + hh], w2 = Wh_n[16 + hh];
                vh0[hh] = vx * w0 + fx * w1 + wx * w2;
                vh1[hh] = vy * w0 + fy * w1 + wy * w2;
                vh2[hh] = vz * w0 + fz * w1 + wz * w2;
                nrm[hh] = sqrtf(fmaxf(vh0[hh]*vh0[hh] + vh1[hh]*vh1[hh] + vh2[hh]*vh2[hh], 1e-8f));
            }

            float sin_[14];
            sin_[0] = cosf(ang[0]); sin_[1] = cosf(ang[1]); sin_[2] = cosf(ang[2]);
            sin_[3] = sinf(ang[0]); sin_[4] = sinf(ang[1]); sin_[5] = sinf(ang[2]);
#pragma unroll
            for (int hh = 0; hh < 8; ++hh) sin_[6 + hh] = nrm[hh];

            const int o0 = lane;
            const int o1 = lane + 64;
            const int o1c = (o1 < 100) ? o1 : 99;
            float acc0 = bs_n[o0];
            float acc1 = bs_n[o1c];
#pragma unroll
            for (int k = 0; k < 14; ++k) {
                acc0 = fmaf(sin_[k], Ws_n[k * 100 + o0], acc0);
                acc1 = fmaf(sin_[k], Ws_n[k * 100 + o1c], acc1);
            }
            const bool has1 = (o1 < 100);
            const float su = wsum64(acc0 + (has1 ? acc1 : 0.f));
            const float mu = su / 100.0f;
            const float d0 = acc0 - mu, d1 = acc1 - mu;
            const float var = wsum64(d0 * d0 + (has1 ? d1 * d1 : 0.f)) / 100.0f;
            const float rstd = 1.0f / sqrtf(var + 1e-3f);

            const size_t vb = (size_t)row * VDIM;
            outV[vb + 24 + o0] = d0 * rstd * gamma_n[o0] + beta_n[o0];
            if (has1) outV[vb + 24 + o1] = d1 * rstd * gamma_n[o1] + beta_n[o1];

            if (lane < 24) {
                const int x = lane >> 3, hh = lane & 7;
                const float* vhx = (x == 0) ? vh0 : ((x == 1) ? vh1 : vh2);
                float vo = 0.f;
#pragma unroll
                for (int k = 0; k < 8; ++k) vo = fmaf(vhx[k], Wv_n[k * 8 + hh], vo);
                outV[vb + lane] = vo;
            }
        }
    }
}

extern "C" void kernel_launch(void* const* d_in, const int* in_sizes, int n_in,
                              void* d_out, int out_size, void* d_ws, size_t ws_size,
                              hipStream_t stream) {
    const float* X       = (const float*)d_in[0];
    const float* Wh_n    = (const float*)d_in[2];
    const float* Ws_n    = (const float*)d_in[3];
    const float* bs_n    = (const float*)d_in[4];
    const float* Wv_n    = (const float*)d_in[5];
    const float* Wh_e    = (const float*)d_in[6];
    const float* Ws_e    = (const float*)d_in[7];
    const float* bs_e    = (const float*)d_in[8];
    const float* Wv_e    = (const float*)d_in[9];
    const float* gamma_n = (const float*)d_in[10];
    const float* beta_n  = (const float*)d_in[11];
    const float* gamma_e = (const float*)d_in[12];
    const float* beta_e  = (const float*)d_in[13];

    float* outV   = (float*)d_out;
    float* outE   = outV + (size_t)BATCH * NN * VDIM;
    float* outIdx = outE + (size_t)BATCH * NN * TOPK * EDIM;

    hipLaunchKernelGGL(fused_kernel, dim3(BATCH * NN / 8), dim3(256), 0, stream,
                       X, Wh_n, Ws_n, bs_n, Wv_n, Wh_e, Ws_e, bs_e, Wv_e,
                       gamma_n, beta_n, gamma_e, beta_e, outV, outE, outIdx);
}

// Round 11
// 68.038 us; speedup vs baseline: 1.4426x; 1.4426x over previous
//
#include <hip/hip_runtime.h>

#define BATCH 4
#define NN    2048
#define TOPK  30
#define VDIM  124
#define EDIM  35

typedef unsigned long long ull;
typedef unsigned int uint;
typedef float f32x2 __attribute__((ext_vector_type(2)));
typedef float f32x4 __attribute__((ext_vector_type(4)));
#define SENT   (~0ull)
#define SENTHI 0xFFFFFFFFu
#define INV2PI 0.15915494309189535f

__device__ __forceinline__ float rnorm3_eps(float s) {
    return 1.0f / sqrtf(fmaxf(s, 1e-8f));
}

__device__ __forceinline__ float wsum64(float v) {
#pragma unroll
    for (int m = 32; m; m >>= 1) v += __shfl_xor(v, m);
    return v;
}

__device__ __forceinline__ uint med3u(uint a, uint b, uint c) {
    uint d;
    asm("v_med3_u32 %0, %1, %2, %3" : "=v"(d) : "v"(a), "v"(b), "v"(c));
    return d;
}

__device__ __forceinline__ ull min64(ull a, ull b) { return a < b ? a : b; }
__device__ __forceinline__ ull max64(ull a, ull b) { return a < b ? b : a; }

__device__ __forceinline__ float rl(float v, int l) {
    return __uint_as_float((uint)__builtin_amdgcn_readlane((int)__float_as_uint(v), l));
}

// full-wave u32 min; result valid in lane 63.
__device__ __forceinline__ uint wmin_u32(uint v) {
    uint t;
    t = (uint)__builtin_amdgcn_update_dpp((int)v, (int)v, 0x111, 0xf, 0xf, false); v = v < t ? v : t; // row_shr:1
    t = (uint)__builtin_amdgcn_update_dpp((int)v, (int)v, 0x112, 0xf, 0xf, false); v = v < t ? v : t; // row_shr:2
    t = (uint)__builtin_amdgcn_update_dpp((int)v, (int)v, 0x114, 0xf, 0xf, false); v = v < t ? v : t; // row_shr:4
    t = (uint)__builtin_amdgcn_update_dpp((int)v, (int)v, 0x118, 0xf, 0xf, false); v = v < t ? v : t; // row_shr:8
    t = (uint)__builtin_amdgcn_update_dpp((int)v, (int)v, 0x142, 0xf, 0xf, false); v = v < t ? v : t; // row_bcast:15
    t = (uint)__builtin_amdgcn_update_dpp((int)v, (int)v, 0x143, 0xf, 0xf, false); v = v < t ? v : t; // row_bcast:31
    return v;
}

// exact pinned squared distance bits (reference f32 order) — refill + conversion.
__device__ __forceinline__ uint d2_bits(const float* __restrict__ sx,
                                        const float2* __restrict__ syz, int j,
                                        float cx, float cy, float cz) {
    const float  x  = sx[j];
    const float2 yz = syz[j];
    const float dx = x - cx, dy = yz.x - cy, dz = yz.y - cz;
    const float d2 = __fadd_rn(__fadd_rn(__fmul_rn(dx, dx), __fmul_rn(dy, dy)),
                               __fmul_rn(dz, dz));
    return __float_as_uint(d2);
}

// exact D bits: sqrt(d2 + 1e-6)
__device__ __forceinline__ uint d2_to_D(uint d2b) {
    return __float_as_uint(sqrtf(__fadd_rn(__uint_as_float(d2b), 1e-6f)));
}

__device__ __forceinline__ void ld_atom(const float* __restrict__ Xb, int f,
                                        float& x, float& y, float& z) {
    const int q = f / 3, r = f - q * 3;
    const float* p = Xb + q * 15 + r * 3;
    x = p[0]; y = p[1]; z = p[2];
}

// ===== fused kernel: 4 rows per 256-thread block; wave w owns row + node =====
__global__ __launch_bounds__(256) void fused_kernel(
    const float* __restrict__ X,
    const float* __restrict__ Wh_n, const float* __restrict__ Ws_n,
    const float* __restrict__ bs_n, const float* __restrict__ Wv_n,
    const float* __restrict__ Wh_e, const float* __restrict__ Ws_e,
    const float* __restrict__ bs_e, const float* __restrict__ Wv_e,
    const float* __restrict__ gamma_n, const float* __restrict__ beta_n,
    const float* __restrict__ gamma_e, const float* __restrict__ beta_e,
    float* __restrict__ outV, float* __restrict__ outE, float* __restrict__ outIdx)
{
    __shared__ float  sCAx[NN];               // 8 KB
    __shared__ float2 sCAyz[NN];              // 16 KB
    __shared__ __align__(16) float sEP[96];   // bs_e | gamma_e | beta_e

    const int tid = threadIdx.x;
    const int row = blockIdx.x * 4 + (tid >> 6);
    const int b   = row >> 11;
    const int i   = row & (NN - 1);
    const int lane = tid & 63;
    const float* Xb = X + (size_t)b * NN * 15;

    for (int idx = tid; idx < NN; idx += 256) {
        const float* p = Xb + idx * 15 + 3;
        sCAx[idx]  = p[0];
        sCAyz[idx] = make_float2(p[1], p[2]);
    }
    if (tid < 32) {
        sEP[tid]      = bs_e[tid];
        sEP[32 + tid] = gamma_e[tid];
        sEP[64 + tid] = beta_e[tid];
    }
    __syncthreads();

    const float cix = sCAx[i];
    const float2 ciyz = sCAyz[i];
    const float ciy = ciyz.x, ciz = ciyz.y;

    // ---- Phase A: per-lane top-4 via med3 insertion on coarse keys.
    // key = (fast-d2 bits & ~31) | s : low 5 mantissa bits (rel ~4e-6) traded
    // for the sub-tile index; unique per lane -> no duplicates. Survivors get
    // exact pinned D recomputed below, so cross-lane selection stays bit-exact.
    uint k0 = SENTHI, k1 = SENTHI, k2 = SENTHI, k3 = SENTHI;
#pragma unroll 8
    for (int s = 0; s < NN / 64; ++s) {
        const int j = (s << 6) + lane;
        const float  x  = sCAx[j];
        const float2 yz = sCAyz[j];
        const float dx = x - cix, dy = yz.x - ciy, dz = yz.y - ciz;
        const float d2 = fmaf(dz, dz, fmaf(dy, dy, dx * dx));   // fast form (coarsened)
        const uint key = (__float_as_uint(d2) & 0xFFFFFFE0u) | (uint)s;
        const uint n0 = (key < k0) ? key : k0;
        const uint n1 = med3u(key, k0, k1);
        const uint n2 = med3u(key, k1, k2);
        const uint n3 = med3u(key, k2, k3);
        k0 = n0; k1 = n1; k2 = n2; k3 = n3;
    }

    // convert survivors to exact (D bits, j) and sort lexicographically (5-CE net)
    ull K0, K1, K2, K3;
    {
        const uint j0 = ((k0 & 31u) << 6) | (uint)lane;
        const uint j1 = ((k1 & 31u) << 6) | (uint)lane;
        const uint j2 = ((k2 & 31u) << 6) | (uint)lane;
        const uint j3 = ((k3 & 31u) << 6) | (uint)lane;
        K0 = (((ull)d2_to_D(d2_bits(sCAx, sCAyz, (int)j0, cix, ciy, ciz))) << 32) | j0;
        K1 = (((ull)d2_to_D(d2_bits(sCAx, sCAyz, (int)j1, cix, ciy, ciz))) << 32) | j1;
        K2 = (((ull)d2_to_D(d2_bits(sCAx, sCAyz, (int)j2, cix, ciy, ciz))) << 32) | j2;
        K3 = (((ull)d2_to_D(d2_bits(sCAx, sCAyz, (int)j3, cix, ciy, ciz))) << 32) | j3;
#define CE(a, b) { const ull mn = min64(a, b), mx = max64(a, b); a = mn; b = mx; }
        CE(K0, K1) CE(K2, K3) CE(K0, K2) CE(K1, K3) CE(K1, K2)
#undef CE
    }
    uint l0hi = (uint)(K0 >> 32), l0lo = (uint)K0;
    uint l1hi = (uint)(K1 >> 32), l1lo = (uint)K1;
    uint l2hi = (uint)(K2 >> 32), l2lo = (uint)K2;
    uint l3hi = (uint)(K3 >> 32), l3lo = (uint)K3;

    // ---- Phase B: 30 extractions in exact D-space; lanes 2e,2e+1 latch edge e
    uint myhi = SENTHI, mylo = 0u;
    for (int it = 0; it < TOPK; ++it) {
        const uint mhi = (uint)__builtin_amdgcn_readlane((int)wmin_u32(l0hi), 63);
        const ull bal = __ballot(l0hi == mhi);
        uint mlo;
        if (__popcll(bal) == 1) {
            mlo = (uint)__builtin_amdgcn_readlane((int)l0lo, __ffsll((long long)bal) - 1);
        } else {
            const uint lom = (l0hi == mhi) ? l0lo : 0xFFFFFFFFu;
            mlo = (uint)__builtin_amdgcn_readlane((int)wmin_u32(lom), 63);
        }
        if ((lane >> 1) == it) { myhi = mhi; mylo = mlo; }

        const bool own = (l0hi == mhi) && (l0lo == mlo);
        if (own) {
            l0hi = l1hi; l0lo = l1lo;
            l1hi = l2hi; l1lo = l2lo;
            l2hi = l3hi; l2lo = l3lo;
            l3hi = SENTHI; l3lo = 0;
        }

        const bool need = own && (l0hi == SENTHI);
        if (__any((int)need)) {                 // rare deep-refill (exact D keys)
            const ull m = (((ull)mhi) << 32) | mlo;
            ull best = SENT;
#pragma unroll 4
            for (int s = 0; s < NN / 64; ++s) {
                const int j = (s << 6) + lane;
                const ull k = (((ull)d2_to_D(d2_bits(sCAx, sCAyz, j, cix, ciy, ciz))) << 32) | (uint)j;
                if (k > m && k < best) best = k;
            }
            if (need) { l0hi = (uint)(best >> 32); l0lo = (uint)best; }
        }
    }

    // ---- Phase C: lanes 2e (h=0) / 2e+1 (h=1) split edge e's 32 LN outputs
    if (lane < 2 * TOPK) {
        const int e = lane >> 1, h = lane & 1;
        const uint j = mylo;
        const float D = __uint_as_float(myhi);

        const float xj = sCAx[j];
        const float2 yzj = sCAyz[j];
        const float ux = xj - cix, uy = yzj.x - ciy, uz = yzj.y - ciz;
        const float inv = rnorm3_eps(ux * ux + uy * uy + uz * uz);

        const float whe = Wh_e[0], wve = Wv_e[0];
        const float hx = ux * inv * whe, hy = uy * inv * whe, hz = uz * inv * whe;
        const float vno = sqrtf(fmaxf(hx * hx + hy * hy + hz * hz, 1e-8f));

        float sx[33];
#pragma unroll
        for (int r = 0; r < 16; ++r) {
            const float t = (D - (float)(20.0 * r / 15.0)) * 0.8f;
            sx[r] = __expf(-t * t);
        }
        const float FRT[8] = {1.0f, 0.31622776601683794f, 0.1f,
                              0.031622776601683794f, 0.01f,
                              0.0031622776601683794f, 0.001f,
                              0.00031622776601683794f};
        const float offset = (float)(int)j - (float)i;
#pragma unroll
        for (int p = 0; p < 8; ++p) {
            const float ang = offset * FRT[p];
            const float rev = __builtin_amdgcn_fractf(ang * INV2PI);
            sx[16 + p] = __builtin_amdgcn_cosf(rev);
            sx[24 + p] = __builtin_amdgcn_sinf(rev);
        }
        sx[32] = vno;

        const int ob = h * 16;
        f32x4 acc4[4];
        const f32x4* bs4 = (const f32x4*)&sEP[ob];
#pragma unroll
        for (int q = 0; q < 4; ++q) acc4[q] = bs4[q];
#pragma unroll
        for (int k = 0; k < 33; ++k) {
            const f32x4* w4 = (const f32x4*)&Ws_e[k * 32 + ob];  // L1-broadcast, b128 loads
            const float v = sx[k];
            const f32x4 vv = {v, v, v, v};
#pragma unroll
            for (int q = 0; q < 4; ++q)
                acc4[q] = __builtin_elementwise_fma(vv, w4[q], acc4[q]);
        }

        float su = 0.f;
#pragma unroll
        for (int q = 0; q < 4; ++q) su += acc4[q][0] + acc4[q][1] + acc4[q][2] + acc4[q][3];
        su += __shfl_xor(su, 1);
        const float mu = su * (1.0f / 32.0f);
        float vs = 0.f;
#pragma unroll
        for (int q = 0; q < 4; ++q) {
#pragma unroll
            for (int r4 = 0; r4 < 4; ++r4) {
                const float d = acc4[q][r4] - mu;
                vs += d * d;
            }
        }
        vs += __shfl_xor(vs, 1);
        const float rstd = 1.0f / sqrtf(vs * (1.0f / 32.0f) + 1e-3f);

        const size_t ebase = ((size_t)row * TOPK + e) * EDIM;
        if (h == 0) {
            outE[ebase + 0] = hx * wve;
            outE[ebase + 1] = hy * wve;
            outE[ebase + 2] = hz * wve;
            outIdx[(size_t)row * TOPK + e] = (float)j;
        }
#pragma unroll
        for (int o = 0; o < 16; ++o)
            outE[ebase + 3 + ob + o] =
                (acc4[o >> 2][o & 3] - mu) * rstd * sEP[32 + ob + o] + sEP[64 + ob + o];
    }

    // ================= NODE features for node = row (same wave) =================
    {
        const int n = i;
        const float* Xr = Xb + n * 15;

        float nx = Xr[0] - Xr[3], ny = Xr[1] - Xr[4], nz = Xr[2] - Xr[5];
        float cx = Xr[6] - Xr[3], cy = Xr[7] - Xr[4], cz = Xr[8] - Xr[5];
        {
            const float ic = rnorm3_eps(cx * cx + cy * cy + cz * cz);
            cx *= ic; cy *= ic; cz *= ic;
            const float in_ = rnorm3_eps(nx * nx + ny * ny + nz * nz);
            nx *= in_; ny *= in_; nz *= in_;
        }
        float bx = cx + nx, by = cy + ny, bz = cz + nz;
        {
            const float ib = rnorm3_eps(bx * bx + by * by + bz * bz);
            bx *= ib; by *= ib; bz *= ib;
        }
        float px = cy * nz - cz * ny, py = cz * nx - cx * nz, pz = cx * ny - cy * nx;
        {
            const float ip = rnorm3_eps(px * px + py * py + pz * pz);
            px *= ip; py *= ip; pz *= ip;
        }
        const float S13 = 0.5773502691896258f, S23 = 0.816496580927726f;
        const float vx = -bx * S13 - px * S23;
        const float vy = -by * S13 - py * S23;
        const float vz = -bz * S13 - pz * S23;

        // fwd/bwd from staged CA (bit-identical values)
        float fx = 0.f, fy = 0.f, fz = 0.f, wx = 0.f, wy = 0.f, wz = 0.f;
        if (n < NN - 1) {
            const float xn = sCAx[n + 1];
            const float2 yzn = sCAyz[n + 1];
            float tx = xn - cix, ty = yzn.x - ciy, tz = yzn.y - ciz;
            const float it = rnorm3_eps(tx * tx + ty * ty + tz * tz);
            fx = tx * it; fy = ty * it; fz = tz * it;
        }
        if (n > 0) {
            const float xp = sCAx[n - 1];
            const float2 yzp = sCAyz[n - 1];
            float tx = cix - xp, ty = ciy - yzp.x, tz = ciz - yzp.y;
            const float it = rnorm3_eps(tx * tx + ty * ty + tz * tz);
            wx = -tx * it; wy = -ty * it; wz = -tz * it;
        }

        // dihedrals lane-parallel: lane t in {0,1,2} computes torsion m = 3n+t-1;
        // ONE instruction stream instead of three serial bodies.
        float cA, sA;
        {
            const int tt = (lane < 3) ? lane : 0;
            const int m = 3 * n + tt - 1;
            const bool valid = (m >= 0) && (m <= 3 * NN - 4);
            const int ms = valid ? m : 1;
            float a0x, a0y, a0z, a1x, a1y, a1z, a2x, a2y, a2z, a3x, a3y, a3z;
            ld_atom(Xb, ms,     a0x, a0y, a0z);
            ld_atom(Xb, ms + 1, a1x, a1y, a1z);
            ld_atom(Xb, ms + 2, a2x, a2y, a2z);
            ld_atom(Xb, ms + 3, a3x, a3y, a3z);
            float u2x = a1x - a0x, u2y = a1y - a0y, u2z = a1z - a0z;
            float u1x = a2x - a1x, u1y = a2y - a1y, u1z = a2z - a1z;
            float u0x = a3x - a2x, u0y = a3y - a2y, u0z = a3z - a2z;
            { const float s = rnorm3_eps(u2x*u2x + u2y*u2y + u2z*u2z); u2x*=s; u2y*=s; u2z*=s; }
            { const float s = rnorm3_eps(u1x*u1x + u1y*u1y + u1z*u1z); u1x*=s; u1y*=s; u1z*=s; }
            { const float s = rnorm3_eps(u0x*u0x + u0y*u0y + u0z*u0z); u0x*=s; u0y*=s; u0z*=s; }
            float n2x = u2y*u1z - u2z*u1y, n2y = u2z*u1x - u2x*u1z, n2z = u2x*u1y - u2y*u1x;
            float n1x = u1y*u0z - u1z*u0y, n1y = u1z*u0x - u1x*u0z, n1z = u1x*u0y - u1y*u0x;
            { const float s = rnorm3_eps(n2x*n2x + n2y*n2y + n2z*n2z); n2x*=s; n2y*=s; n2z*=s; }
            { const float s = rnorm3_eps(n1x*n1x + n1y*n1y + n1z*n1z); n1x*=s; n1y*=s; n1z*=s; }
            float cd = n2x*n1x + n2y*n1y + n2z*n1z;
            cd = fminf(fmaxf(cd, -1.0f + 1e-7f), 1.0f - 1e-7f);
            const float sg0 = u2x*n1x + u2y*n1y + u2z*n1z;
            const float sg = (sg0 > 0.f) ? 1.f : ((sg0 < 0.f) ? -1.f : 0.f);
            const float ang = valid ? sg * acosf(cd) : 0.f;
            cA = cosf(ang);
            sA = sinf(ang);
        }

        float vh0[8], vh1[8], vh2[8], nrm[8];
#pragma unroll
        for (int hh = 0; hh < 8; ++hh) {
            const float w0 = Wh_n[hh], w1 = Wh_n[8 + hh], w2 = Wh_n[16 + hh];
            vh0[hh] = vx * w0 + fx * w1 + wx * w2;
            vh1[hh] = vy * w0 + fy * w1 + wy * w2;
            vh2[hh] = vz * w0 + fz * w1 + wz * w2;
            nrm[hh] = sqrtf(fmaxf(vh0[hh]*vh0[hh] + vh1[hh]*vh1[hh] + vh2[hh]*vh2[hh], 1e-8f));
        }

        float sin_[14];
        sin_[0] = rl(cA, 0); sin_[1] = rl(cA, 1); sin_[2] = rl(cA, 2);
        sin_[3] = rl(sA, 0); sin_[4] = rl(sA, 1); sin_[5] = rl(sA, 2);
#pragma unroll
        for (int hh = 0; hh < 8; ++hh) sin_[6 + hh] = nrm[hh];

        const int o0 = lane;
        const int o1 = lane + 64;
        const int o1c = (o1 < 100) ? o1 : 99;
        float acc0 = bs_n[o0];
        float acc1 = bs_n[o1c];
#pragma unroll
        for (int k = 0; k < 14; ++k) {
            acc0 = fmaf(sin_[k], Ws_n[k * 100 + o0], acc0);
            acc1 = fmaf(sin_[k], Ws_n[k * 100 + o1c], acc1);
        }
        const bool has1 = (o1 < 100);
        const float su = wsum64(acc0 + (has1 ? acc1 : 0.f));
        const float mu = su / 100.0f;
        const float d0 = acc0 - mu, d1 = acc1 - mu;
        const float var = wsum64(d0 * d0 + (has1 ? d1 * d1 : 0.f)) / 100.0f;
        const float rstd = 1.0f / sqrtf(var + 1e-3f);

        const size_t vb = (size_t)row * VDIM;
        outV[vb + 24 + o0] = d0 * rstd * gamma_n[o0] + beta_n[o0];
        if (has1) outV[vb + 24 + o1] = d1 * rstd * gamma_n[o1] + beta_n[o1];

        if (lane < 24) {
            const int x = lane >> 3, hh = lane & 7;
            const float* vhx = (x == 0) ? vh0 : ((x == 1) ? vh1 : vh2);
            float vo = 0.f;
#pragma unroll
            for (int k = 0; k < 8; ++k) vo = fmaf(vhx[k], Wv_n[k * 8 + hh], vo);
            outV[vb + lane] = vo;
        }
    }
}

extern "C" void kernel_launch(void* const* d_in, const int* in_sizes, int n_in,
                              void* d_out, int out_size, void* d_ws, size_t ws_size,
                              hipStream_t stream) {
    const float* X       = (const float*)d_in[0];
    const float* Wh_n    = (const float*)d_in[2];
    const float* Ws_n    = (const float*)d_in[3];
    const float* bs_n    = (const float*)d_in[4];
    const float* Wv_n    = (const float*)d_in[5];
    const float* Wh_e    = (const float*)d_in[6];
    const float* Ws_e    = (const float*)d_in[7];
    const float* bs_e    = (const float*)d_in[8];
    const float* Wv_e    = (const float*)d_in[9];
    const float* gamma_n = (const float*)d_in[10];
    const float* beta_n  = (const float*)d_in[11];
    const float* gamma_e = (const float*)d_in[12];
    const float* beta_e  = (const float*)d_in[13];

    float* outV   = (float*)d_out;
    float* outE   = outV + (size_t)BATCH * NN * VDIM;
    float* outIdx = outE + (size_t)BATCH * NN * TOPK * EDIM;

    hipLaunchKernelGGL(fused_kernel, dim3(BATCH * NN / 4), dim3(256), 0, stream,
                       X, Wh_n, Ws_n, bs_n, Wv_n, Wh_e, Ws_e, bs_e, Wv_e,
                       gamma_n, beta_n, gamma_e, beta_e, outV, outE, outIdx);
}